// Round 1
// baseline (9728.241 us; speedup 1.0000x reference)
//
#include <hip/hip_runtime.h>

// ---------------- ws layout (float offsets) ----------------
// [0]                : dtype flag (int: 1 = bf16 inputs, 0 = fp32 inputs)
// [16 .. 16+8192)    : Wc = W1 @ W_enc   [64][128] fp32
// [8208 .. +64)      : bc = W1 @ b_enc   [64] fp32
// [8272 .. +1024)    : bias = b_ih+b_hh  [1024] fp32
// [16384 .. +3276800): blend1 [1024][50][64] fp32   (~13.2 MB total ws use)
#define O_WC     16
#define O_BC     (16 + 8192)
#define O_BIAS   (O_BC + 64)
#define O_BLEND1 16384

#define NEG_INF_V (-1.0e9f)

__device__ __forceinline__ float b2f(unsigned int u) {
  union { unsigned int i; float f; } x; x.i = u << 16; return x.f;
}
__device__ __forceinline__ float b2fh(unsigned int u) {
  union { unsigned int i; float f; } x; x.i = u & 0xffff0000u; return x.f;
}
__device__ __forceinline__ unsigned short f2b(float f) {
  union { float f; unsigned int i; } x; x.f = f;
  unsigned int r = x.i + 0x7fffu + ((x.i >> 16) & 1u);
  return (unsigned short)(r >> 16);
}
__device__ __forceinline__ float ldv(const void* p, int b16, int i) {
  if (b16) return b2f(((const unsigned short*)p)[i]);
  return ((const float*)p)[i];
}
struct F8 { float v[8]; };
// load 8 consecutive elements (i must be a multiple of 8) as fp32
__device__ __forceinline__ F8 ld8(const void* p, int b16, int i) {
  F8 r;
  if (b16) {
    uint4 u = *((const uint4*)((const unsigned short*)p + i));
    r.v[0] = b2f(u.x & 0xffffu); r.v[1] = b2fh(u.x);
    r.v[2] = b2f(u.y & 0xffffu); r.v[3] = b2fh(u.y);
    r.v[4] = b2f(u.z & 0xffffu); r.v[5] = b2fh(u.z);
    r.v[6] = b2f(u.w & 0xffffu); r.v[7] = b2fh(u.w);
  } else {
    const float4* q = (const float4*)((const float*)p + i);
    float4 a = q[0], b = q[1];
    r.v[0] = a.x; r.v[1] = a.y; r.v[2] = a.z; r.v[3] = a.w;
    r.v[4] = b.x; r.v[5] = b.y; r.v[6] = b.z; r.v[7] = b.w;
  }
  return r;
}
__device__ __forceinline__ float sigm(float x)  { return 1.0f / (1.0f + __expf(-x)); }
__device__ __forceinline__ float tanhx(float x) { return 1.0f - 2.0f / (1.0f + __expf(2.0f * x)); }
// XOR swizzle: elements are consumed in 8-element chunks with chunk index ≡ s (mod 8);
// phys = j ^ ((j>>3)&7) makes the 8 simultaneous float4 reads hit distinct bank quads.
__device__ __forceinline__ int SW(int j) { return j ^ ((j >> 3) & 7); }

// ---------------- prep0: dtype detect + bias + bc ----------------
__global__ void prep0(const void* b_enc, const void* b_ih, const void* b_hh,
                      const void* W1, float* ws) {
  __shared__ int anybig;
  int t = threadIdx.x;
  if (t == 0) anybig = 0;
  __syncthreads();
  {
    // Read first 512B of b_enc as 256 bf16 slots. If data is fp32, low-half
    // slots are mantissa junk -> |v|>1 (or NaN) with overwhelming probability.
    unsigned short u = ((const unsigned short*)b_enc)[t];
    float f = b2f((unsigned int)u);
    if (!(fabsf(f) <= 1.0f)) atomicOr(&anybig, 1);
  }
  __syncthreads();
  int b16 = anybig ? 0 : 1;
  if (t == 0) ((int*)ws)[0] = b16;
  for (int k = t; k < 1024; k += 256)
    ws[O_BIAS + k] = ldv(b_ih, b16, k) + ldv(b_hh, b16, k);
  if (t < 64) {
    float acc = 0.f;
    for (int h = 0; h < 256; ++h)
      acc += ldv(W1, b16, t * 256 + h) * ldv(b_enc, b16, h);
    ws[O_BC + t] = acc;
  }
}

// ---------------- prep1: Wc = W1 @ W_enc  (32 blocks x 256 thr) ----------------
__global__ void prep1(const void* W_enc, const void* W1, float* ws) {
  int b16 = ((const int*)ws)[0];
  int o = blockIdx.x * 256 + threadIdx.x;   // 0..8191
  int w = o >> 7, i = o & 127;
  float acc = 0.f;
  for (int h = 0; h < 256; ++h)
    acc += ldv(W1, b16, w * 256 + h) * ldv(W_enc, b16, h * 128 + i);
  ws[O_WC + o] = acc;
}

// ---------------- blendk: blend1 = targets @ Wc^T + bc  (1024 blocks) ----------------
__global__ __launch_bounds__(256) void blendk(const void* targets, float* ws) {
  __shared__ float tg[6400];   // 50x128 fp32, one batch row set
  int b16 = ((const int*)ws)[0];
  int t = threadIdx.x, b = blockIdx.x;
  for (int k = t; k < 6400; k += 256) tg[k] = ldv(targets, b16, b * 6400 + k);
  __syncthreads();
  int w = t & 63, j0 = t >> 6;
  for (int j = j0; j < 50; j += 4) {
    float acc = 0.f;
    for (int i0 = 0; i0 < 128; i0 += 8) {
      const float4* q = (const float4*)(ws + O_WC + w * 128 + i0);
      float4 a = q[0], bb = q[1];
      const float* x = &tg[j * 128 + i0];
      acc += a.x * x[0] + a.y * x[1] + a.z * x[2] + a.w * x[3]
           + bb.x * x[4] + bb.y * x[5] + bb.z * x[6] + bb.w * x[7];
    }
    ws[O_BLEND1 + (b * 50 + j) * 64 + w] = acc + ws[O_BC + w];
  }
}

// ---------------- main: 50 sequential steps, 4 batch rows / block ----------------
__global__ __launch_bounds__(512) void mainK(
    const void* targets, const void* h0, const void* c0,
    const void* W_ih, const void* W_hh, const void* W2, const void* vt,
    float* ws, void* outp) {
  __shared__ __align__(16) float xT[128][4];   // dec_in, transposed, XOR-swizzled rows
  __shared__ __align__(16) float hT[256][4];   // h, transposed, XOR-swizzled rows
  __shared__ float cT[4][256];
  __shared__ float gsh[4][1024];               // gates
  __shared__ float bias_s[1024];
  __shared__ float b2s[4][64];                 // blend2
  __shared__ float outs[4][64];
  __shared__ float vt_s[64];
  __shared__ int   selidx[4];
  __shared__ int   selb[4][64];

  const int b16 = ((const int*)ws)[0];
  const int t = threadIdx.x;
  const int bbase = blockIdx.x * 4;

  for (int k = t; k < 1024; k += 512) bias_s[k] = ws[O_BIAS + k];
  for (int k = t; k < 1024; k += 512) {
    int p = k & 3, j = k >> 2;
    hT[SW(j)][p] = ldv(h0, b16, (bbase + p) * 256 + j);
    cT[p][j]     = ldv(c0, b16, (bbase + p) * 256 + j);
  }
  { int p = t & 3, i = t >> 2; xT[SW(i)][p] = 0.f; }
  if (t < 64) vt_s[t] = ldv(vt, b16, t);
  if (t < 256) selb[t >> 6][t & 63] = 0;
  __syncthreads();

  const int s = t & 7, g = (t >> 3) & 7, wv = t >> 6;

  #pragma unroll 1
  for (int step = 0; step < 50; ++step) {
    // ---- phase A: gates = x@W_ih^T + h@W_hh^T  (bias added in A2) ----
    #pragma unroll 1
    for (int pp = 0; pp < 2; ++pp) {
      const int rbase = pp * 512 + wv * 64 + g;   // this lane-group's base row
      float acc[8][4];
      #pragma unroll
      for (int q = 0; q < 8; q++)
        #pragma unroll
        for (int p = 0; p < 4; p++) acc[q][p] = 0.f;

      // input part: K=128 (2 chunk-rounds)
      #pragma unroll
      for (int m = 0; m < 2; ++m) {
        const int e0 = 64 * m + 8 * s;
        F8 wr[8];
        #pragma unroll
        for (int q = 0; q < 8; q++) wr[q] = ld8(W_ih, b16, (rbase + 8 * q) * 128 + e0);
        #pragma unroll
        for (int e = 0; e < 8; e++) {
          float4 xv = *(const float4*)&xT[SW(e0 + e)][0];
          #pragma unroll
          for (int q = 0; q < 8; q++) {
            float wq = wr[q].v[e];
            acc[q][0] += wq * xv.x; acc[q][1] += wq * xv.y;
            acc[q][2] += wq * xv.z; acc[q][3] += wq * xv.w;
          }
        }
      }
      // hidden part: K=256 (4 chunk-rounds)
      #pragma unroll
      for (int m = 0; m < 4; ++m) {
        const int e0 = 64 * m + 8 * s;
        F8 wr[8];
        #pragma unroll
        for (int q = 0; q < 8; q++) wr[q] = ld8(W_hh, b16, (rbase + 8 * q) * 256 + e0);
        #pragma unroll
        for (int e = 0; e < 8; e++) {
          float4 hv = *(const float4*)&hT[SW(e0 + e)][0];
          #pragma unroll
          for (int q = 0; q < 8; q++) {
            float wq = wr[q].v[e];
            acc[q][0] += wq * hv.x; acc[q][1] += wq * hv.y;
            acc[q][2] += wq * hv.z; acc[q][3] += wq * hv.w;
          }
        }
      }
      // butterfly-reduce over the 8 K-slices (lanes xor 1,2,4)
      #pragma unroll
      for (int msk = 1; msk < 8; msk <<= 1)
        #pragma unroll
        for (int q = 0; q < 8; q++)
          #pragma unroll
          for (int p = 0; p < 4; p++)
            acc[q][p] += __shfl_xor(acc[q][p], msk, 64);
      // lane s writes row rbase + 8*s (select chain avoids dynamic reg index)
      {
        const int row = rbase + 8 * s;
        #pragma unroll
        for (int q = 0; q < 8; q++)
          if (s == q) {
            gsh[0][row] = acc[q][0]; gsh[1][row] = acc[q][1];
            gsh[2][row] = acc[q][2]; gsh[3][row] = acc[q][3];
          }
      }
    }
    __syncthreads();

    // ---- phase A2: LSTM pointwise ----
    for (int k = t; k < 1024; k += 512) {
      int j = k & 255, p = k >> 8;
      float gi = sigm (gsh[p][j]       + bias_s[j]);
      float gf = sigm (gsh[p][256 + j] + bias_s[256 + j]);
      float gg = tanhx(gsh[p][512 + j] + bias_s[512 + j]);
      float go = sigm (gsh[p][768 + j] + bias_s[768 + j]);
      float c = gf * cT[p][j] + gi * gg;
      cT[p][j] = c;
      hT[SW(j)][p] = go * tanhx(c);
    }
    __syncthreads();

    // ---- phase B: blend2 = h @ W2^T ----
    if (t < 256) {
      int w = t & 63, p = t >> 6;
      float acc = 0.f;
      for (int j0 = 0; j0 < 256; j0 += 8) {
        F8 wr = ld8(W2, b16, w * 256 + j0);
        #pragma unroll
        for (int e = 0; e < 8; e++) acc += wr.v[e] * hT[SW(j0 + e)][p];
      }
      b2s[p][w] = acc;
    }
    __syncthreads();

    // ---- phase C: out = vt . tanh(blend1 + blend2), mask ----
    if (t < 200) {
      int p = t / 50, j = t % 50;
      const float* bl = ws + O_BLEND1 + ((bbase + p) * 50 + j) * 64;
      float acc = 0.f;
      #pragma unroll 8
      for (int w = 0; w < 64; w++) acc += vt_s[w] * tanhx(bl[w] + b2s[p][w]);
      outs[p][j] = selb[p][j] ? NEG_INF_V : acc;
    }
    __syncthreads();
    // ---- argmax + softmax + write probs, update selected ----
    if (t < 256) {
      int p = t >> 6, lane = t & 63;
      float v = (lane < 50) ? outs[p][lane] : -3.4e38f;
      int idx = lane;
      #pragma unroll
      for (int msk = 1; msk < 64; msk <<= 1) {
        float ov = __shfl_xor(v, msk, 64);
        int   oi = __shfl_xor(idx, msk, 64);
        if (ov > v || (ov == v && oi < idx)) { v = ov; idx = oi; }
      }
      float e = (lane < 50) ? __expf(outs[p][lane] - v) : 0.f;
      float ssum = e;
      #pragma unroll
      for (int msk = 1; msk < 64; msk <<= 1) ssum += __shfl_xor(ssum, msk, 64);
      if (lane < 50) {
        float prob = fmaxf(e / ssum, 1e-9f);
        int o = (bbase + p) * 2500 + step * 50 + lane;
        if (b16) ((unsigned short*)outp)[o] = f2b(prob);
        else     ((float*)outp)[o] = prob;
      }
      if (lane == 0) selidx[p] = idx;
      if (lane == idx) selb[p][idx] = 1;
    }
    __syncthreads();
    // ---- phase D: dec_in = targets[b, sel_idx] ----
    {
      int p = t >> 7, i = t & 127;
      xT[SW(i)][p] = ldv(targets, b16, ((bbase + p) * 50 + selidx[p]) * 128 + i);
    }
    __syncthreads();
  }
}

extern "C" void kernel_launch(void* const* d_in, const int* in_sizes, int n_in,
                              void* d_out, int out_size, void* d_ws, size_t ws_size,
                              hipStream_t stream) {
  (void)in_sizes; (void)n_in; (void)out_size; (void)ws_size;
  const void* targets = d_in[0];
  const void* h0      = d_in[1];
  const void* c0      = d_in[2];
  const void* W_enc   = d_in[3];
  const void* b_enc   = d_in[4];
  const void* W_ih    = d_in[5];
  const void* W_hh    = d_in[6];
  const void* b_ih    = d_in[7];
  const void* b_hh    = d_in[8];
  const void* W1      = d_in[9];
  const void* W2      = d_in[10];
  const void* vt      = d_in[11];
  float* ws = (float*)d_ws;

  prep0<<<1, 256, 0, stream>>>(b_enc, b_ih, b_hh, W1, ws);
  prep1<<<32, 256, 0, stream>>>(W_enc, W1, ws);
  blendk<<<1024, 256, 0, stream>>>(targets, ws);
  mainK<<<256, 512, 0, stream>>>(targets, h0, c0, W_ih, W_hh, W2, vt, ws, d_out);
}

// Round 2
// 1607.351 us; speedup vs baseline: 6.0523x; 6.0523x over previous
//
#include <hip/hip_runtime.h>

// ---------------- ws layout (float offsets) ----------------
// [0]        : dtype flag (int: 1 = bf16 inputs, 0 = fp32 inputs)
// O_WC       : Wc = W1 @ W_enc   [64][128] fp32
// O_BC       : bc = W1 @ b_enc   [64] fp32
// O_BIAS     : bias = b_ih+b_hh  [1024] fp32
// O_BLEND1   : blend1 [1024][50][64] fp32
// O_XW       : xw [1024][50][1024] fp32 (200MB; only if ws_size permits)
#define O_WC     16
#define O_BC     (16 + 8192)
#define O_BIAS   (O_BC + 64)
#define O_BLEND1 16384
#define O_XW     4194304
#define XW_FLOATS 52428800ULL   // 1024*50*1024
#define NEG_INF_V (-1.0e9f)

__device__ __forceinline__ float b2f(unsigned int u) {
  union { unsigned int i; float f; } x; x.i = u << 16; return x.f;
}
__device__ __forceinline__ unsigned short f2b(float f) {
  union { float f; unsigned int i; } x; x.f = f;
  unsigned int r = x.i + 0x7fffu + ((x.i >> 16) & 1u);
  return (unsigned short)(r >> 16);
}
__device__ __forceinline__ float ldv(const void* p, int b16, long long i) {
  if (b16) return b2f(((const unsigned short*)p)[i]);
  return ((const float*)p)[i];
}
__device__ __forceinline__ float sigm(float x)  { return 1.0f / (1.0f + __expf(-x)); }
__device__ __forceinline__ float tanhx(float x) { return 1.0f - 2.0f / (1.0f + __expf(2.0f * x)); }
// XOR swizzle so 8 simultaneous float4 broadcasts (one per K-slice s) hit
// distinct bank quads. phys = j ^ ((j>>3)&7).
__device__ __forceinline__ int SW(int j) { return j ^ ((j >> 3) & 7); }

// select bf16 element e (0..7) out of a uint4, e must be unroll-constant
__device__ __forceinline__ float bfsel(const uint4& u, int e) {
  unsigned int w = (e < 2) ? u.x : (e < 4) ? u.y : (e < 6) ? u.z : u.w;
  union { unsigned int i; float f; } x;
  x.i = (e & 1) ? (w & 0xffff0000u) : (w << 16);
  return x.f;
}
#define FMA4(A, F, H) { A.x += (F)*(H).x; A.y += (F)*(H).y; A.z += (F)*(H).z; A.w += (F)*(H).w; }

// acc 4 rows (row0..row0+3) x 4 batch over NM*64 K-elems, K-slice s (8 slices
// of 8-elem chunks). Weights read direct from global (bf16 packed, lazily
// unpacked: keeps live set ~16 regs for weights). hb is the swizzled
// [K][4] LDS buffer.
template<int NM, int LDW>
__device__ __forceinline__ void rows4_bf16(
    const unsigned short* W, int row0, int s, const float (*hb)[4],
    float4& a0, float4& a1, float4& a2, float4& a3) {
  const unsigned short* p0 = W + (long long)row0 * LDW + 8 * s;
  #pragma unroll 2
  for (int m = 0; m < NM; ++m) {
    const int e0 = 64 * m + 8 * s;
    uint4 w0 = *(const uint4*)(p0 + 64 * m);
    uint4 w1 = *(const uint4*)(p0 + LDW + 64 * m);
    uint4 w2 = *(const uint4*)(p0 + 2 * LDW + 64 * m);
    uint4 w3 = *(const uint4*)(p0 + 3 * LDW + 64 * m);
    #pragma unroll
    for (int e = 0; e < 8; ++e) {
      const float4 hv = *(const float4*)&hb[SW(e0 + e)][0];
      float f0 = bfsel(w0, e); FMA4(a0, f0, hv);
      float f1 = bfsel(w1, e); FMA4(a1, f1, hv);
      float f2 = bfsel(w2, e); FMA4(a2, f2, hv);
      float f3 = bfsel(w3, e); FMA4(a3, f3, hv);
    }
  }
}
template<int NM, int LDW>
__device__ __forceinline__ void rows4_f32(
    const float* W, int row0, int s, const float (*hb)[4],
    float4& a0, float4& a1, float4& a2, float4& a3) {
  #pragma unroll 2
  for (int m = 0; m < NM; ++m) {
    const int e0 = 64 * m + 8 * s;
    #pragma unroll
    for (int e = 0; e < 8; ++e) {
      const float4 hv = *(const float4*)&hb[SW(e0 + e)][0];
      float f0 = W[(long long)(row0 + 0) * LDW + e0 + e]; FMA4(a0, f0, hv);
      float f1 = W[(long long)(row0 + 1) * LDW + e0 + e]; FMA4(a1, f1, hv);
      float f2 = W[(long long)(row0 + 2) * LDW + e0 + e]; FMA4(a2, f2, hv);
      float f3 = W[(long long)(row0 + 3) * LDW + e0 + e]; FMA4(a3, f3, hv);
    }
  }
}

// ---------------- prep0: dtype detect + bias + bc ----------------
__global__ void prep0(const void* b_enc, const void* b_ih, const void* b_hh,
                      const void* W1, float* ws) {
  __shared__ int anybig;
  int t = threadIdx.x;
  if (t == 0) anybig = 0;
  __syncthreads();
  {
    unsigned short u = ((const unsigned short*)b_enc)[t];
    float f = b2f((unsigned int)u);
    if (!(fabsf(f) <= 1.0f)) atomicOr(&anybig, 1);
  }
  __syncthreads();
  int b16 = anybig ? 0 : 1;
  if (t == 0) ((int*)ws)[0] = b16;
  for (int k = t; k < 1024; k += 256)
    ws[O_BIAS + k] = ldv(b_ih, b16, k) + ldv(b_hh, b16, k);
  if (t < 64) {
    float acc = 0.f;
    for (int h = 0; h < 256; ++h)
      acc += ldv(W1, b16, t * 256 + h) * ldv(b_enc, b16, h);
    ws[O_BC + t] = acc;
  }
}

// ---------------- prep1: Wc = W1 @ W_enc ----------------
__global__ void prep1(const void* W_enc, const void* W1, float* ws) {
  int b16 = ((const int*)ws)[0];
  int o = blockIdx.x * 256 + threadIdx.x;
  int w = o >> 7, i = o & 127;
  float acc = 0.f;
  for (int h = 0; h < 256; ++h)
    acc += ldv(W1, b16, w * 256 + h) * ldv(W_enc, b16, h * 128 + i);
  ws[O_WC + o] = acc;
}

// ---------------- blendk: blend1 = targets @ Wc^T + bc ----------------
__global__ __launch_bounds__(256) void blendk(const void* targets, float* ws) {
  __shared__ float tg[6400];
  int b16 = ((const int*)ws)[0];
  int t = threadIdx.x, b = blockIdx.x;
  if (b16) {
    const unsigned short* tp = (const unsigned short*)targets + (long long)b * 6400;
    for (int k = t * 8; k < 6400; k += 2048) {
      uint4 u = *(const uint4*)(tp + k);
      #pragma unroll
      for (int e = 0; e < 8; ++e) tg[k + e] = bfsel(u, e);
    }
  } else {
    const float* tp = (const float*)targets + (long long)b * 6400;
    for (int k = t; k < 6400; k += 256) tg[k] = tp[k];
  }
  __syncthreads();
  int w = t & 63, j0 = t >> 6;
  for (int j = j0; j < 50; j += 4) {
    float acc = 0.f;
    for (int i0 = 0; i0 < 128; i0 += 8) {
      const float4* q = (const float4*)(ws + O_WC + w * 128 + i0);
      float4 a = q[0], bb = q[1];
      const float* x = &tg[j * 128 + i0];
      acc += a.x * x[0] + a.y * x[1] + a.z * x[2] + a.w * x[3]
           + bb.x * x[4] + bb.y * x[5] + bb.z * x[6] + bb.w * x[7];
    }
    ws[O_BLEND1 + (b * 50 + j) * 64 + w] = acc + ws[O_BC + w];
  }
}

// ---------------- xwK: xw[b][j][r] = targets[b,j,:] . W_ih[r,:] ----------------
// one block per batch row; W_ih staged per 64-row chunk in LDS (fp32, pad 132).
__global__ __launch_bounds__(256) void xwK(const void* targets, const void* W_ih,
                                           float* ws) {
  __shared__ float tgl[64 * 132];
  __shared__ float wl[64 * 132];
  const int b16 = ((const int*)ws)[0];
  const int t = threadIdx.x, b = blockIdx.x;
  float* xwp = ws + O_XW + (unsigned long long)b * 51200ULL;

  // stage targets[b] (50x128 -> padded 132), zero rows 50..63
  if (b16) {
    const unsigned short* tp = (const unsigned short*)targets + (long long)b * 6400;
    for (int k = t * 8; k < 6400; k += 2048) {
      int j = k >> 7, i0 = k & 127;
      uint4 u = *(const uint4*)(tp + k);
      #pragma unroll
      for (int e = 0; e < 8; ++e) tgl[j * 132 + i0 + e] = bfsel(u, e);
    }
  } else {
    const float* tp = (const float*)targets + (long long)b * 6400;
    for (int k = t; k < 6400; k += 256) tgl[(k >> 7) * 132 + (k & 127)] = tp[k];
  }
  for (int k = t; k < 14 * 132; k += 256) tgl[50 * 132 + k] = 0.f;

  const int tr = t & 15, tj = t >> 4;
  for (int c = 0; c < 16; ++c) {
    __syncthreads();
    // stage W_ih rows c*64 .. c*64+63
    if (b16) {
      const unsigned short* wp = (const unsigned short*)W_ih + (long long)c * 8192;
      for (int k = t * 8; k < 8192; k += 2048) {
        int r = k >> 7, i0 = k & 127;
        uint4 u = *(const uint4*)(wp + k);
        #pragma unroll
        for (int e = 0; e < 8; ++e) wl[r * 132 + i0 + e] = bfsel(u, e);
      }
    } else {
      const float* wp = (const float*)W_ih + (long long)c * 8192;
      for (int k = t; k < 8192; k += 256) wl[(k >> 7) * 132 + (k & 127)] = wp[k];
    }
    __syncthreads();
    float a[4][4];
    #pragma unroll
    for (int rr = 0; rr < 4; rr++)
      #pragma unroll
      for (int jj = 0; jj < 4; jj++) a[rr][jj] = 0.f;
    for (int i0 = 0; i0 < 128; i0 += 4) {
      float4 wv0 = *(const float4*)&wl[(tr + 0)  * 132 + i0];
      float4 wv1 = *(const float4*)&wl[(tr + 16) * 132 + i0];
      float4 wv2 = *(const float4*)&wl[(tr + 32) * 132 + i0];
      float4 wv3 = *(const float4*)&wl[(tr + 48) * 132 + i0];
      #pragma unroll
      for (int jj = 0; jj < 4; jj++) {
        float4 tv = *(const float4*)&tgl[(tj + 16 * jj) * 132 + i0];
        a[0][jj] += wv0.x * tv.x + wv0.y * tv.y + wv0.z * tv.z + wv0.w * tv.w;
        a[1][jj] += wv1.x * tv.x + wv1.y * tv.y + wv1.z * tv.z + wv1.w * tv.w;
        a[2][jj] += wv2.x * tv.x + wv2.y * tv.y + wv2.z * tv.z + wv2.w * tv.w;
        a[3][jj] += wv3.x * tv.x + wv3.y * tv.y + wv3.z * tv.z + wv3.w * tv.w;
      }
    }
    #pragma unroll
    for (int jj = 0; jj < 4; jj++) {
      int j = tj + 16 * jj;
      if (j < 50) {
        #pragma unroll
        for (int rr = 0; rr < 4; rr++)
          xwp[j * 1024 + c * 64 + tr + 16 * rr] = a[rr][jj];
      }
    }
  }
}

// ---------------- main: 50 sequential steps, 4 batch rows / block ----------------
__global__ __launch_bounds__(512) void mainK(
    const void* targets, const void* h0, const void* c0,
    const void* W_ih, const void* W_hh, const void* W2, const void* vt,
    float* ws, void* outp, int use_xw) {
  __shared__ __align__(16) float xT[128][4];
  __shared__ __align__(16) float hT[256][4];
  __shared__ float cT[4][256];
  __shared__ float gsh[4][1024];
  __shared__ float bias_s[1024];
  __shared__ float b2s[4][64];
  __shared__ float outs[4][64];
  __shared__ float vt_s[64];
  __shared__ int   selidx[4];
  __shared__ int   selb[4][64];

  const int b16 = ((const int*)ws)[0];
  const int t = threadIdx.x;
  const int bbase = blockIdx.x * 4;
  const float* xw = ws + O_XW;

  for (int k = t; k < 1024; k += 512) bias_s[k] = ws[O_BIAS + k];
  for (int k = t; k < 1024; k += 512) {
    int p = k & 3, j = k >> 2;
    hT[SW(j)][p] = ldv(h0, b16, (bbase + p) * 256 + j);
    cT[p][j]     = ldv(c0, b16, (bbase + p) * 256 + j);
  }
  { int p = t & 3, i = t >> 2; xT[SW(i)][p] = 0.f; }
  if (t < 64) vt_s[t] = ldv(vt, b16, t);
  if (t < 256) selb[t >> 6][t & 63] = 0;
  if (t < 4) selidx[t] = -1;
  __syncthreads();

  const int s = t & 7, G = t >> 3;   // K-slice, row-group (0..63)

  #pragma unroll 1
  for (int step = 0; step < 50; ++step) {
    // ---- phase A: gsh = h@W_hh^T (+ x@W_ih^T when no xw table) ----
    #pragma unroll 1
    for (int pass = 0; pass < 4; ++pass) {
      const int row0 = pass * 256 + G * 4;
      float4 a0 = {0,0,0,0}, a1 = {0,0,0,0}, a2 = {0,0,0,0}, a3 = {0,0,0,0};
      if (b16) {
        if (!use_xw)
          rows4_bf16<2,128>((const unsigned short*)W_ih, row0, s, xT, a0,a1,a2,a3);
        rows4_bf16<4,256>((const unsigned short*)W_hh, row0, s, hT, a0,a1,a2,a3);
      } else {
        if (!use_xw)
          rows4_f32<2,128>((const float*)W_ih, row0, s, xT, a0,a1,a2,a3);
        rows4_f32<4,256>((const float*)W_hh, row0, s, hT, a0,a1,a2,a3);
      }
      #pragma unroll
      for (int msk = 1; msk < 8; msk <<= 1) {
        a0.x += __shfl_xor(a0.x, msk, 64); a0.y += __shfl_xor(a0.y, msk, 64);
        a0.z += __shfl_xor(a0.z, msk, 64); a0.w += __shfl_xor(a0.w, msk, 64);
        a1.x += __shfl_xor(a1.x, msk, 64); a1.y += __shfl_xor(a1.y, msk, 64);
        a1.z += __shfl_xor(a1.z, msk, 64); a1.w += __shfl_xor(a1.w, msk, 64);
        a2.x += __shfl_xor(a2.x, msk, 64); a2.y += __shfl_xor(a2.y, msk, 64);
        a2.z += __shfl_xor(a2.z, msk, 64); a2.w += __shfl_xor(a2.w, msk, 64);
        a3.x += __shfl_xor(a3.x, msk, 64); a3.y += __shfl_xor(a3.y, msk, 64);
        a3.z += __shfl_xor(a3.z, msk, 64); a3.w += __shfl_xor(a3.w, msk, 64);
      }
      if (s < 4) {
        #pragma unroll
        for (int q = 0; q < 4; q++)
          if (s == q) {
            float4 aq = (q == 0) ? a0 : (q == 1) ? a1 : (q == 2) ? a2 : a3;
            gsh[0][row0 + q] = aq.x; gsh[1][row0 + q] = aq.y;
            gsh[2][row0 + q] = aq.z; gsh[3][row0 + q] = aq.w;
          }
      }
    }
    __syncthreads();

    // ---- phase A2: LSTM pointwise (adds gathered x@W_ih^T row) ----
    for (int k = t; k < 1024; k += 512) {
      int j = k & 255, p = k >> 8;
      float gi = gsh[p][j], gf = gsh[p][256 + j];
      float gg = gsh[p][512 + j], go = gsh[p][768 + j];
      if (use_xw) {
        int sv = selidx[p];
        if (sv >= 0) {
          const float* xr = xw + (((unsigned long long)(bbase + p)) * 50 + sv) * 1024ULL;
          gi += xr[j]; gf += xr[256 + j]; gg += xr[512 + j]; go += xr[768 + j];
        }
      }
      gi = sigm (gi + bias_s[j]);
      gf = sigm (gf + bias_s[256 + j]);
      gg = tanhx(gg + bias_s[512 + j]);
      go = sigm (go + bias_s[768 + j]);
      float c = gf * cT[p][j] + gi * gg;
      cT[p][j] = c;
      hT[SW(j)][p] = go * tanhx(c);
    }
    __syncthreads();

    // ---- mini-pass: blend2 = h @ W2^T (row per group) ----
    {
      float4 bq = {0,0,0,0};
      if (b16) {
        const unsigned short* p0 = (const unsigned short*)W2 + G * 256 + 8 * s;
        #pragma unroll 2
        for (int m = 0; m < 4; ++m) {
          const int e0 = 64 * m + 8 * s;
          uint4 w0 = *(const uint4*)(p0 + 64 * m);
          #pragma unroll
          for (int e = 0; e < 8; ++e) {
            const float4 hv = *(const float4*)&hT[SW(e0 + e)][0];
            float f0 = bfsel(w0, e); FMA4(bq, f0, hv);
          }
        }
      } else {
        const float* p0 = (const float*)W2 + G * 256;
        for (int m = 0; m < 4; ++m) {
          const int e0 = 64 * m + 8 * s;
          #pragma unroll
          for (int e = 0; e < 8; ++e) {
            const float4 hv = *(const float4*)&hT[SW(e0 + e)][0];
            float f0 = p0[e0 + e]; FMA4(bq, f0, hv);
          }
        }
      }
      #pragma unroll
      for (int msk = 1; msk < 8; msk <<= 1) {
        bq.x += __shfl_xor(bq.x, msk, 64); bq.y += __shfl_xor(bq.y, msk, 64);
        bq.z += __shfl_xor(bq.z, msk, 64); bq.w += __shfl_xor(bq.w, msk, 64);
      }
      if (s == 0) {
        b2s[0][G] = bq.x; b2s[1][G] = bq.y; b2s[2][G] = bq.z; b2s[3][G] = bq.w;
      }
    }
    __syncthreads();

    // ---- phase C: out = vt . tanh(blend1 + blend2), mask ----
    if (t < 400) {
      int o = t >> 1, sp = t & 1;
      int p = o / 50, j = o - p * 50;
      const float* bl = ws + O_BLEND1 + (((bbase + p) * 50 + j) * 64) + sp * 32;
      float acc = 0.f;
      #pragma unroll 8
      for (int w = 0; w < 32; w++)
        acc += vt_s[sp * 32 + w] * tanhx(bl[w] + b2s[p][sp * 32 + w]);
      acc += __shfl_xor(acc, 1, 64);
      if (sp == 0) outs[p][j] = selb[p][j] ? NEG_INF_V : acc;
    }
    __syncthreads();

    // ---- argmax + softmax + write probs, update selected ----
    if (t < 256) {
      int p = t >> 6, lane = t & 63;
      float v = (lane < 50) ? outs[p][lane] : -3.4e38f;
      int idx = lane;
      #pragma unroll
      for (int msk = 1; msk < 64; msk <<= 1) {
        float ov = __shfl_xor(v, msk, 64);
        int   oi = __shfl_xor(idx, msk, 64);
        if (ov > v || (ov == v && oi < idx)) { v = ov; idx = oi; }
      }
      float e = (lane < 50) ? __expf(outs[p][lane] - v) : 0.f;
      float ssum = e;
      #pragma unroll
      for (int msk = 1; msk < 64; msk <<= 1) ssum += __shfl_xor(ssum, msk, 64);
      if (lane < 50) {
        float prob = fmaxf(e / ssum, 1e-9f);
        int o = (bbase + p) * 2500 + step * 50 + lane;
        if (b16) ((unsigned short*)outp)[o] = f2b(prob);
        else     ((float*)outp)[o] = prob;
      }
      if (lane == 0) selidx[p] = idx;
      if (lane == idx) selb[p][idx] = 1;
    }
    __syncthreads();

    // ---- phase D (fallback only): dec_in gather into xT ----
    if (!use_xw) {
      int p = t >> 7, i = t & 127;
      xT[SW(i)][p] = ldv(targets, b16, ((long long)(bbase + p) * 50 + selidx[p]) * 128 + i);
      __syncthreads();
    }
  }
}

extern "C" void kernel_launch(void* const* d_in, const int* in_sizes, int n_in,
                              void* d_out, int out_size, void* d_ws, size_t ws_size,
                              hipStream_t stream) {
  (void)in_sizes; (void)n_in; (void)out_size;
  const void* targets = d_in[0];
  const void* h0      = d_in[1];
  const void* c0      = d_in[2];
  const void* W_enc   = d_in[3];
  const void* b_enc   = d_in[4];
  const void* W_ih    = d_in[5];
  const void* W_hh    = d_in[6];
  const void* b_ih    = d_in[7];
  const void* b_hh    = d_in[8];
  const void* W1      = d_in[9];
  const void* W2      = d_in[10];
  const void* vt      = d_in[11];
  float* ws = (float*)d_ws;

  int use_xw = (ws_size >= ((size_t)O_XW + (size_t)XW_FLOATS) * 4) ? 1 : 0;

  prep0<<<1, 256, 0, stream>>>(b_enc, b_ih, b_hh, W1, ws);
  prep1<<<32, 256, 0, stream>>>(W_enc, W1, ws);
  blendk<<<1024, 256, 0, stream>>>(targets, ws);
  if (use_xw) xwK<<<1024, 256, 0, stream>>>(targets, W_ih, ws);
  mainK<<<256, 512, 0, stream>>>(targets, h0, c0, W_ih, W_hh, W2, vt, ws, d_out,
                                 use_xw);
}